// Round 1
// baseline (878.154 us; speedup 1.0000x reference)
//
#include <hip/hip_runtime.h>
#include <hip/hip_bf16.h>
#include <math.h>

// ---------------------------------------------------------------------------
// WindowAttention (dual-lambda linear attention) for MI355X / gfx950
//   B=2048, N=64 tokens, C=384, H=12 heads, d=32
//   Pipeline: setup (weight repack bf16 + lambda) -> qkv+attention fused
//             -> output projection GEMM
// ---------------------------------------------------------------------------

typedef __attribute__((ext_vector_type(8))) short short8;   // 8 x bf16
typedef __attribute__((ext_vector_type(4))) float f32x4;

#define MFMA_BF16(A,B,C) __builtin_amdgcn_mfma_f32_16x16x32_bf16(A,B,C,0,0,0)

__device__ __forceinline__ unsigned short f2bf(float f) {
  unsigned int u = __float_as_uint(f);
  u += 0x7FFFu + ((u >> 16) & 1u);            // round-to-nearest-even
  return (unsigned short)(u >> 16);
}

#define BB 2048
#define NN 64
#define CC 384
#define HH 12
#define DD 32

// workspace byte offsets (total ~101.9 MB)
#define WS_O    0                         // bf16 [131072][384]  = 100663296 B
#define WS_WT   100663296                 // bf16 [12][96][384]  =    884736 B
#define WS_W2T  101548032                 // bf16 [384][384]     =    294912 B
#define WS_WB   101842944                 // f32  [12][96]       =      4608 B
#define WS_LAM  101847552                 // f32  [12]           =        48 B

// ---------------------------------------------------------------------------
// setup: repack qkv_w -> WT[h][c][k] (c: 0-31 q, 32-63 k, 64-95 v),
//        proj_w -> W2T[n][k], biases -> Wb[h][c], lamS[h] = 1 - lambda_full
// ---------------------------------------------------------------------------
__global__ void setup_kernel(const float* __restrict__ qkv_w,
                             const float* __restrict__ qkv_b,
                             const float* __restrict__ proj_w,
                             const float* __restrict__ lk1, const float* __restrict__ lv1,
                             const float* __restrict__ lk2, const float* __restrict__ lv2,
                             unsigned short* __restrict__ WT,
                             unsigned short* __restrict__ W2T,
                             float* __restrict__ Wb,
                             float* __restrict__ lamS)
{
  const int nWT  = HH * 96 * CC;   // 442368
  const int nW2T = CC * CC;        // 147456
  const int nWb  = HH * 96;        // 1152
  int gid = blockIdx.x * 256 + threadIdx.x;
  if (gid < nWT) {
    int h = gid / (96 * CC);
    int r = gid % (96 * CC);
    int c = r / CC;
    int k = r % CC;
    int col = (c >> 5) * CC + h * DD + (c & 31);      // q/k/v block, head, dim
    WT[gid] = f2bf(qkv_w[(size_t)k * (3 * CC) + col]);
  } else if (gid < nWT + nW2T) {
    int j = gid - nWT;
    int n = j / CC, k = j % CC;
    W2T[j] = f2bf(proj_w[(size_t)k * CC + n]);
  } else if (gid < nWT + nW2T + nWb) {
    int j = gid - nWT - nW2T;
    int h = j / 96, c = j % 96;
    Wb[j] = qkv_b[(c >> 5) * CC + h * DD + (c & 31)];
  } else if (gid < nWT + nW2T + nWb + HH) {
    int h = gid - nWT - nW2T - nWb;
    float s1 = 0.f, s2 = 0.f;
    for (int i = 0; i < DD; ++i) {
      s1 += lk1[h * DD + i] * lv1[h * DD + i];
      s2 += lk2[h * DD + i] * lv2[h * DD + i];
    }
    float lambda_init = 0.8f - 0.6f * __expf(-0.3f);
    float lam = __expf(s1) - __expf(s2) + lambda_init;
    lamS[h] = 1.0f - lam;                             // attn = (1-lambda)*A
  }
}

// ---------------------------------------------------------------------------
// fused qkv projection + per-head linear attention
// grid: 2048 blocks (one per batch element), 256 threads (4 waves)
// LDS: Xs [64][392] bf16 (50176 B)   x_b, padded vs bank conflicts
//      region at +50176 (14848 B): Wt [96][72] during GEMM,
//                                  then S [64][96] + At [32][40]
// ---------------------------------------------------------------------------
__global__ __launch_bounds__(256, 2) void qkv_attn_kernel(
    const float* __restrict__ x,
    const unsigned short* __restrict__ WT,
    const float* __restrict__ Wb,
    const float* __restrict__ lamS,
    unsigned short* __restrict__ O)
{
  __shared__ __align__(16) char smem[65024];
  unsigned short* Xs = (unsigned short*)smem;                    // [64][392]
  unsigned short* Wt = (unsigned short*)(smem + 50176);          // [96][72]
  unsigned short* S  = (unsigned short*)(smem + 50176);          // [64][96]
  unsigned short* At = (unsigned short*)(smem + 50176 + 12288);  // [32][40]

  const int b    = blockIdx.x;
  const int tid  = threadIdx.x;
  const int lane = tid & 63;
  const int wave = tid >> 6;
  const int quad = lane >> 4;
  const int l15  = lane & 15;
  const int m0   = wave * 16;

  // ---- stage x_b: 64x384 fp32 -> bf16, padded row stride 392 ----
  {
    const float* xb = x + (size_t)b * (NN * CC);
    #pragma unroll
    for (int it = 0; it < 24; ++it) {
      int i = it * 256 + tid;
      int row = i / 96, c4 = i % 96;
      float4 v = *(const float4*)(xb + row * CC + c4 * 4);
      ushort4 o;
      o.x = f2bf(v.x); o.y = f2bf(v.y); o.z = f2bf(v.z); o.w = f2bf(v.w);
      *(ushort4*)(Xs + row * 392 + c4 * 4) = o;
    }
  }

  for (int h = 0; h < HH; ++h) {
    const unsigned short* Wh = WT + (size_t)h * (96 * CC);

    uint4 pf[3];
    #pragma unroll
    for (int t = 0; t < 3; ++t) {                 // prefetch K-chunk 0
      int idx = tid + t * 256;
      int c = idx >> 3, seg = idx & 7;
      pf[t] = *(const uint4*)(Wh + c * CC + seg * 8);
    }
    __syncthreads();   // x staged (h==0) / prev head S,At reads done (h>0)
    #pragma unroll
    for (int t = 0; t < 3; ++t) {
      int idx = tid + t * 256;
      int c = idx >> 3, seg = idx & 7;
      *(uint4*)(Wt + c * 72 + seg * 8) = pf[t];
    }
    __syncthreads();

    f32x4 acc[6];
    #pragma unroll
    for (int t = 0; t < 6; ++t) acc[t] = (f32x4){0.f, 0.f, 0.f, 0.f};

    // ---- GEMM: [64 rows] x [96 cols q|k|v] over K=384, chunks of 64 ----
    for (int kc = 0; kc < 6; ++kc) {
      if (kc < 5) {
        #pragma unroll
        for (int t = 0; t < 3; ++t) {
          int idx = tid + t * 256;
          int c = idx >> 3, seg = idx & 7;
          pf[t] = *(const uint4*)(Wh + c * CC + (kc + 1) * 64 + seg * 8);
        }
      }
      #pragma unroll
      for (int step = 0; step < 2; ++step) {
        const int kk = step * 32 + quad * 8;
        short8 a = *(const short8*)(Xs + (m0 + l15) * 392 + kc * 64 + kk);
        #pragma unroll
        for (int t = 0; t < 6; ++t) {
          short8 bfr = *(const short8*)(Wt + (t * 16 + l15) * 72 + kk);
          acc[t] = MFMA_BF16(a, bfr, acc[t]);
        }
      }
      __syncthreads();
      if (kc < 5) {
        #pragma unroll
        for (int t = 0; t < 3; ++t) {
          int idx = tid + t * 256;
          int c = idx >> 3, seg = idx & 7;
          *(uint4*)(Wt + c * 72 + seg * 8) = pf[t];
        }
      }
      __syncthreads();
    }

    // ---- epilogue: +bias, q*=scale / feature map; -> S[n][c] bf16 ----
    #pragma unroll
    for (int t = 0; t < 6; ++t) {
      int c = t * 16 + l15;
      float bias = Wb[h * 96 + c];
      #pragma unroll
      for (int r = 0; r < 4; ++r) {
        int row = m0 + quad * 4 + r;                 // C/D: row = quad*4+reg
        float v = acc[t][r] + bias;
        if (c < 32) v *= 0.17677669529663689f;       // q * d^-0.5
        else        v = (v >= 0.f) ? (v + 1.f) : __expf(v);   // ELU+1
        S[row * 96 + c] = f2bf(v);
      }
    }
    __syncthreads();

    // ---- A[i][e] = sum_n fk[n][i]*fv[n][e]; attn=(1-lam)*gauss*A ----
    {
      const int i0 = (wave & 1) * 16;
      const int e0 = (wave >> 1) * 16;
      f32x4 accA = (f32x4){0.f, 0.f, 0.f, 0.f};
      #pragma unroll
      for (int n0 = 0; n0 < 64; n0 += 32) {
        short8 afr, bfr;
        #pragma unroll
        for (int j = 0; j < 8; ++j) {
          int n = n0 + quad * 8 + j;
          afr[j] = (short)S[n * 96 + 32 + i0 + l15];   // fk^T as A-operand
          bfr[j] = (short)S[n * 96 + 64 + e0 + l15];   // fv as B-operand
        }
        accA = MFMA_BF16(afr, bfr, accA);
      }
      float lsc = lamS[h];
      #pragma unroll
      for (int r = 0; r < 4; ++r) {
        int i = i0 + quad * 4 + r;
        int e = e0 + l15;
        float diff = (float)(i - e);
        float g = __expf(-2.0f * diff * diff);       // sigma=0.5
        At[e * 40 + i] = f2bf(accA[r] * lsc * g);    // At[e][dd]=attn[dd][e]
      }
    }
    __syncthreads();

    // ---- out = q @ attn  (64x32) -> O[b,n, h*32+e] bf16 ----
    {
      const int n0w = wave * 16;
      short8 aq = *(const short8*)(S + (n0w + l15) * 96 + quad * 8);
      #pragma unroll
      for (int t2 = 0; t2 < 2; ++t2) {
        const int e0 = t2 * 16;
        short8 bA = *(const short8*)(At + (e0 + l15) * 40 + quad * 8);
        f32x4 accO = (f32x4){0.f, 0.f, 0.f, 0.f};
        accO = MFMA_BF16(aq, bA, accO);
        #pragma unroll
        for (int r = 0; r < 4; ++r) {
          int n = n0w + quad * 4 + r;
          O[(size_t)(b * NN + n) * CC + h * DD + e0 + l15] = f2bf(accO[r]);
        }
      }
    }
    // next head's first __syncthreads protects S/At before Wt overwrite
  }
}

// ---------------------------------------------------------------------------
// projection GEMM: out[131072][384] = O[131072][384] @ proj_w + proj_b (fp32)
// 128x128 tiles, 4 waves of 64x64, K chunks of 64, register prefetch
// ---------------------------------------------------------------------------
__global__ __launch_bounds__(256, 2) void proj_kernel(
    const unsigned short* __restrict__ O,
    const unsigned short* __restrict__ W2T,
    const float* __restrict__ proj_b,
    float* __restrict__ out)
{
  __shared__ __align__(16) char smem[36864];
  unsigned short* As = (unsigned short*)smem;             // [128][72]
  unsigned short* Bs = (unsigned short*)(smem + 18432);   // [128][72]

  const int bn = blockIdx.x;          // 0..2
  const int bm = blockIdx.y;          // 0..1023
  const int m0 = bm * 128, n0 = bn * 128;
  const int tid  = threadIdx.x;
  const int lane = tid & 63, wave = tid >> 6;
  const int quad = lane >> 4, l15 = lane & 15;
  const int mw = (wave >> 1) * 64, nw = (wave & 1) * 64;

  f32x4 acc[4][4];
  #pragma unroll
  for (int i = 0; i < 4; ++i)
    #pragma unroll
    for (int j = 0; j < 4; ++j) acc[i][j] = (f32x4){0.f, 0.f, 0.f, 0.f};

  uint4 pa[4], pb[4];
  auto ld = [&](int kc) {
    #pragma unroll
    for (int t = 0; t < 4; ++t) {
      int idx = tid + t * 256;
      int r = idx >> 3, seg = idx & 7;
      pa[t] = *(const uint4*)(O   + (size_t)(m0 + r) * CC + kc * 64 + seg * 8);
      pb[t] = *(const uint4*)(W2T + (size_t)(n0 + r) * CC + kc * 64 + seg * 8);
    }
  };
  auto st = [&]() {
    #pragma unroll
    for (int t = 0; t < 4; ++t) {
      int idx = tid + t * 256;
      int r = idx >> 3, seg = idx & 7;
      *(uint4*)(As + r * 72 + seg * 8) = pa[t];
      *(uint4*)(Bs + r * 72 + seg * 8) = pb[t];
    }
  };

  ld(0);
  st();
  __syncthreads();
  for (int kc = 0; kc < 6; ++kc) {
    if (kc < 5) ld(kc + 1);
    #pragma unroll
    for (int step = 0; step < 2; ++step) {
      const int kk = step * 32 + quad * 8;
      short8 af[4], bf_[4];
      #pragma unroll
      for (int t = 0; t < 4; ++t) {
        af[t]  = *(const short8*)(As + (mw + t * 16 + l15) * 72 + kk);
        bf_[t] = *(const short8*)(Bs + (nw + t * 16 + l15) * 72 + kk);
      }
      #pragma unroll
      for (int i = 0; i < 4; ++i)
        #pragma unroll
        for (int j = 0; j < 4; ++j)
          acc[i][j] = MFMA_BF16(af[i], bf_[j], acc[i][j]);
    }
    __syncthreads();
    if (kc < 5) st();
    __syncthreads();
  }

  #pragma unroll
  for (int j = 0; j < 4; ++j) {
    int col = n0 + nw + j * 16 + l15;
    float bias = proj_b[col];
    #pragma unroll
    for (int i = 0; i < 4; ++i) {
      int row0 = m0 + mw + i * 16 + quad * 4;
      #pragma unroll
      for (int r = 0; r < 4; ++r) {
        out[(size_t)(row0 + r) * CC + col] = acc[i][j][r] + bias;
      }
    }
  }
}

// ---------------------------------------------------------------------------
extern "C" void kernel_launch(void* const* d_in, const int* in_sizes, int n_in,
                              void* d_out, int out_size, void* d_ws, size_t ws_size,
                              hipStream_t stream) {
  const float* x      = (const float*)d_in[0];
  const float* qkv_w  = (const float*)d_in[1];
  const float* qkv_b  = (const float*)d_in[2];
  const float* proj_w = (const float*)d_in[3];
  const float* proj_b = (const float*)d_in[4];
  const float* lk1    = (const float*)d_in[5];
  const float* lv1    = (const float*)d_in[6];
  const float* lk2    = (const float*)d_in[7];
  const float* lv2    = (const float*)d_in[8];

  char* ws = (char*)d_ws;                 // needs ~101.9 MB of workspace
  unsigned short* O   = (unsigned short*)(ws + WS_O);
  unsigned short* WT  = (unsigned short*)(ws + WS_WT);
  unsigned short* W2T = (unsigned short*)(ws + WS_W2T);
  float* Wb           = (float*)(ws + WS_WB);
  float* lamS         = (float*)(ws + WS_LAM);

  setup_kernel<<<2309, 256, 0, stream>>>(qkv_w, qkv_b, proj_w,
                                         lk1, lv1, lk2, lv2,
                                         WT, W2T, Wb, lamS);
  qkv_attn_kernel<<<2048, 256, 0, stream>>>(x, WT, Wb, lamS, O);
  proj_kernel<<<dim3(3, 1024), 256, 0, stream>>>(O, W2T, proj_b, (float*)d_out);
}